// Round 12
// baseline (118.745 us; speedup 1.0000x reference)
//
#include <hip/hip_runtime.h>
#include <hip/hip_bf16.h>

#define HH 16
#define DD 128
#define NBQ 128
#define SS 8192

typedef __attribute__((ext_vector_type(4))) float f32x4;
typedef __attribute__((ext_vector_type(4))) short bf16x4;
typedef __attribute__((ext_vector_type(8))) short bf16x8;

// single-instruction HW convert (RNE)
__device__ __forceinline__ short f2bf_hw(float f) {
  __hip_bfloat16 b = __float2bfloat16(f);
  return __builtin_bit_cast(short, b);
}

__device__ __forceinline__ void gload_lds16(const void* g, void* l) {
  __builtin_amdgcn_global_load_lds(
      (const __attribute__((address_space(1))) void*)g,
      (__attribute__((address_space(3))) void*)l, 16, 0, 0);
}

// ---- fused prepass (validated round 8): K fp32->bf16 [h][s][d] AND V -> bf16 Vt [h][kb][d][64] ----
__global__ __launch_bounds__(256)
void conv_kv_kernel(const float* __restrict__ kg, const float* __restrict__ vg,
                    unsigned short* __restrict__ kbuf, unsigned short* __restrict__ vt) {
  __shared__ unsigned short tile[128 * 72];  // [d][s'] with +8 short pad per row
  const int kb = blockIdx.x, h = blockIdx.y, tid = threadIdx.x;
  const int r = tid >> 2, q = tid & 3;
  // ---- K convert (row r, d-chunk q*32..+31) ----
  {
    const float* kp = kg + ((size_t)(kb * 64 + r) * HH + h) * DD + q * 32;
    unsigned short* ko = kbuf + ((size_t)h * SS + (size_t)kb * 64 + r) * DD + q * 32;
    #pragma unroll
    for (int c = 0; c < 4; ++c) {
      f32x4 a = *(const f32x4*)(kp + c * 8);
      f32x4 b = *(const f32x4*)(kp + c * 8 + 4);
      bf16x8 f;
      f[0] = f2bf_hw(a[0]); f[1] = f2bf_hw(a[1]); f[2] = f2bf_hw(a[2]); f[3] = f2bf_hw(a[3]);
      f[4] = f2bf_hw(b[0]); f[5] = f2bf_hw(b[1]); f[6] = f2bf_hw(b[2]); f[7] = f2bf_hw(b[3]);
      *(bf16x8*)(ko + c * 8) = f;
    }
  }
  // ---- V transpose into LDS tile ----
  {
    const float* vp = vg + ((size_t)(kb * 64 + r) * HH + h) * DD + q * 32;
    #pragma unroll
    for (int c = 0; c < 8; ++c) {
      f32x4 a = *(const f32x4*)(vp + c * 4);
      #pragma unroll
      for (int j = 0; j < 4; ++j)
        tile[(q * 32 + c * 4 + j) * 72 + r] = (unsigned short)f2bf_hw(a[j]);
    }
  }
  __syncthreads();
  const int d = tid >> 1, half = tid & 1;
  unsigned short* op = vt + ((size_t)(h * NBQ + kb) * 128 + d) * 64 + half * 32;
  #pragma unroll
  for (int j = 0; j < 4; ++j)
    *(bf16x8*)(op + j * 8) = *(const bf16x8*)(&tile[d * 72 + half * 32 + j * 8]);
}

// ------------- main kernel: v10-verified core; LPT dispatch order (heavy qgrp first) -------------
// 1 workgroup = (2 q-blocks, head), 4 waves x 32 rows. Swapped QK^T, in-register P,
// PV via 16x16x16 K-steps. 48KB LDS: K single-buffered, V double-buffered ->
// 3 workgroups/CU. qgrp = 63 - (bx>>4), h = bx&15: heavy workgroups dispatch first.
#define SWK(o) ((o) ^ ((((o) >> 8) & 7) << 4))
#define SWV(o) ((o) ^ ((((o) >> 7) & 7) << 4))

__global__ __launch_bounds__(256, 2)
void sparse_attn_v11(const float* __restrict__ qg_, const unsigned short* __restrict__ kbuf,
                     const unsigned short* __restrict__ vtbuf, float* __restrict__ outg) {
  extern __shared__ __align__(16) char lds[];
  // Ks: 0..16KB ([64 key][128 d] bf16 swz) | V buf b (b=0,1): 16384 + b*16384 ([128 d][64 key] swz)

  const int bx   = blockIdx.x;
  const int qgrp = (NBQ / 2 - 1) - (bx >> 4);   // LPT: heavy (large nlist) first
  const int h    = bx & 15;
  const int tid  = threadIdx.x;
  const int wid  = tid >> 6;
  const int lane = tid & 63;
  const int l15  = lane & 15;
  const int lg   = lane >> 4;

  const int qlo  = qgrp * 2, qhi = qgrp * 2 + 1;
  const int qb_w = qlo + (wid >> 1);          // this wave's q-block
  const int rib0 = (wid & 1) * 32;            // wave's row base within its q-block

  const int nv     = (qhi + 1 < 4) ? qhi + 1 : 4;
  const int wstart = (qlo - 3 > 4) ? qlo - 3 : 4;
  const int nw     = (qhi - wstart + 1 > 0) ? qhi - wstart + 1 : 0;
  const int nlist  = nv + nw;

  // 1/sqrt(128) * log2(e): exp2-domain softmax
  const float scale = 0.12752030522080552f;

  // ---- Q fragments (B operand: col j = q-row = l15, k = d = kc*32+lg*8+{0..7}) ----
  bf16x8 qa[2][4];
  #pragma unroll
  for (int m = 0; m < 2; ++m) {
    const float* qp = qg_ + ((size_t)(qgrp * 128 + wid * 32 + m * 16 + l15) * HH + h) * DD;
    #pragma unroll
    for (int kc = 0; kc < 4; ++kc) {
      const int d0 = kc * 32 + lg * 8;
      f32x4 a = *(const f32x4*)(qp + d0);
      f32x4 b = *(const f32x4*)(qp + d0 + 4);
      bf16x8 f;
      f[0] = f2bf_hw(a[0] * scale); f[1] = f2bf_hw(a[1] * scale);
      f[2] = f2bf_hw(a[2] * scale); f[3] = f2bf_hw(a[3] * scale);
      f[4] = f2bf_hw(b[0] * scale); f[5] = f2bf_hw(b[1] * scale);
      f[6] = f2bf_hw(b[2] * scale); f[7] = f2bf_hw(b[3] * scale);
      qa[m][kc] = f;
    }
  }

  // oa[m][nd][r] = O[q-row = lg*4+r (of m-tile)][d = nd*16+l15]
  f32x4 oa[2][8];
  #pragma unroll
  for (int m = 0; m < 2; ++m)
    #pragma unroll
    for (int i = 0; i < 8; ++i) oa[m][i] = (f32x4){0.f, 0.f, 0.f, 0.f};
  float mr[2] = {-1e30f, -1e30f};   // running row max, keyed q-row = l15 (row-uniform)
  float lr[2] = {0.f, 0.f};         // lane-partial row sum, keyed l15

  const char* kbase = (const char*)kbuf + ((size_t)h * NBQ << 14);
  const char* vbase = (const char*)vtbuf + ((size_t)h * NBQ << 14);

  // prologue: stage list[0] (= block 0): K -> Ks, V -> vbuf0
  {
    #pragma unroll
    for (int p = 0; p < 4; ++p) {
      const int ob = p * 4096 + wid * 1024;
      const int o  = ob + lane * 16;
      gload_lds16(kbase + SWK(o), lds + ob);
      gload_lds16(vbase + SWV(o), lds + 16384 + ob);
    }
  }
  __syncthreads();

  for (int t = 0; t < nlist; ++t) {
    const int kb = (t < nv) ? t : (wstart + (t - nv));
    const bool valid = (kb <= qb_w) && ((qb_w - kb < 4) || (kb < 4));
    char* Vb = lds + 16384 + (t & 1) * 16384;

    // ---- S^T = K Q^T : s[m][kt][r] = S[q=l15 (m-tile)][key = kt*16+lg*4+r] ----
    f32x4 s[2][4];
    if (valid) {
      #pragma unroll
      for (int m = 0; m < 2; ++m)
        #pragma unroll
        for (int kt = 0; kt < 4; ++kt) s[m][kt] = (f32x4){0.f, 0.f, 0.f, 0.f};
      __builtin_amdgcn_s_setprio(1);
      #pragma unroll
      for (int kt = 0; kt < 4; ++kt) {
        const int key = kt * 16 + l15;   // A-frag row = l15
        #pragma unroll
        for (int kc = 0; kc < 4; ++kc) {
          const int off = (key * 256 + (kc * 32 + lg * 8) * 2) ^ ((key & 7) << 4);
          bf16x8 kf = *(const bf16x8*)(lds + off);   // A: K[key][d]  (Ks at base 0)
          s[0][kt] = __builtin_amdgcn_mfma_f32_16x16x32_bf16(kf, qa[0][kc], s[0][kt], 0, 0, 0);
          s[1][kt] = __builtin_amdgcn_mfma_f32_16x16x32_bf16(kf, qa[1][kc], s[1][kt], 0, 0, 0);
        }
      }
      __builtin_amdgcn_s_setprio(0);
    }

    __syncthreads();   // barrier1: all waves done reading Ks (no vmem outstanding -> cheap)

    // ---- issue async stages for t+1: K(t+1) -> Ks (safe now), V(t+1) -> other V buf ----
    if (t + 1 < nlist) {
      const int kbn = (t + 1 < nv) ? (t + 1) : (wstart + (t + 1 - nv));
      const char* ksrc = kbase + ((size_t)kbn << 14);
      const char* vsrc = vbase + ((size_t)kbn << 14);
      char* Vd = lds + 16384 + ((t + 1) & 1) * 16384;
      #pragma unroll
      for (int p = 0; p < 4; ++p) {
        const int ob = p * 4096 + wid * 1024;
        const int o  = ob + lane * 16;
        gload_lds16(ksrc + SWK(o), lds + ob);
        gload_lds16(vsrc + SWV(o), Vd + ob);
      }
    }

    if (valid) {
      // ---- diagonal block: element-level causal mask (q = l15, key = kt*16+lg*4+r) ----
      if (kb == qb_w) {
        #pragma unroll
        for (int m = 0; m < 2; ++m) {
          const int rib = rib0 + m * 16 + l15;   // q-row within block
          #pragma unroll
          for (int kt = 0; kt < 4; ++kt)
            #pragma unroll
            for (int r = 0; r < 4; ++r) {
              const int key = kt * 16 + lg * 4 + r;
              if (rib < key) s[m][kt][r] = -1e30f;
            }
        }
      }

      // ---- softmax (exp2 domain, defer-max THR=8, lane-partial sum) ----
      #pragma unroll
      for (int m = 0; m < 2; ++m) {
        float a0 = fmaxf(fmaxf(s[m][0][0], s[m][0][1]), fmaxf(s[m][0][2], s[m][0][3]));
        float a1 = fmaxf(fmaxf(s[m][1][0], s[m][1][1]), fmaxf(s[m][1][2], s[m][1][3]));
        float a2 = fmaxf(fmaxf(s[m][2][0], s[m][2][1]), fmaxf(s[m][2][2], s[m][2][3]));
        float a3 = fmaxf(fmaxf(s[m][3][0], s[m][3][1]), fmaxf(s[m][3][2], s[m][3][3]));
        float lanemax = fmaxf(fmaxf(a0, a1), fmaxf(a2, a3));
        if (!__all(lanemax <= mr[m] + 8.f)) {
          float mx = lanemax;
          mx = fmaxf(mx, __shfl_xor(mx, 16));
          mx = fmaxf(mx, __shfl_xor(mx, 32));     // row max (uniform across lg)
          const float mnew = fmaxf(mr[m], mx);
          const float sc = __builtin_amdgcn_exp2f(mr[m] - mnew);
          lr[m] *= sc;                             // lr keyed l15: direct
          mr[m] = mnew;
          // transpose sc to oa rows: row (lg*4+r)'s sc lives in lane (lg*4+r)
          const float s0 = __shfl(sc, lg * 4 + 0);
          const float s1 = __shfl(sc, lg * 4 + 1);
          const float s2 = __shfl(sc, lg * 4 + 2);
          const float s3 = __shfl(sc, lg * 4 + 3);
          #pragma unroll
          for (int nd = 0; nd < 8; ++nd) {
            oa[m][nd][0] *= s0; oa[m][nd][1] *= s1;
            oa[m][nd][2] *= s2; oa[m][nd][3] *= s3;
          }
        }
        float lsum = 0.f;
        #pragma unroll
        for (int kt = 0; kt < 4; ++kt)
          #pragma unroll
          for (int r = 0; r < 4; ++r) {
            const float p = __builtin_amdgcn_exp2f(s[m][kt][r] - mr[m]);
            s[m][kt][r] = p;
            lsum += p;
          }
        lr[m] += lsum;
      }

      // ---- pack P in-register: pa[m][kt] = A-frag (row=l15, k=lg*4+{0..3}) ----
      bf16x4 pa[2][4];
      #pragma unroll
      for (int m = 0; m < 2; ++m)
        #pragma unroll
        for (int kt = 0; kt < 4; ++kt) {
          unsigned u0 = (unsigned)(unsigned short)f2bf_hw(s[m][kt][0]) |
                        ((unsigned)(unsigned short)f2bf_hw(s[m][kt][1]) << 16);
          unsigned u1 = (unsigned)(unsigned short)f2bf_hw(s[m][kt][2]) |
                        ((unsigned)(unsigned short)f2bf_hw(s[m][kt][3]) << 16);
          uint2 uu; uu.x = u0; uu.y = u1;
          pa[m][kt] = __builtin_bit_cast(bf16x4, uu);
        }

      // ---- O += P V : 4 K-steps of 16x16x16; V b64 B-frags (keys kt*16+lg*4+{0..3}) ----
      __builtin_amdgcn_s_setprio(1);
      #pragma unroll
      for (int nd = 0; nd < 8; ++nd) {
        const int d = nd * 16 + l15;
        #pragma unroll
        for (int kt = 0; kt < 4; ++kt) {
          const int off = (d * 128 + (kt * 16 + lg * 4) * 2) ^ ((d & 7) << 4);
          bf16x4 vfr = *(const bf16x4*)(Vb + off);
          oa[0][nd] = __builtin_amdgcn_mfma_f32_16x16x16bf16_1k(pa[0][kt], vfr, oa[0][nd], 0, 0, 0);
          oa[1][nd] = __builtin_amdgcn_mfma_f32_16x16x16bf16_1k(pa[1][kt], vfr, oa[1][nd], 0, 0, 0);
        }
      }
      __builtin_amdgcn_s_setprio(0);
    }
    __syncthreads();  // barrier2: drains K/V DMA; protects Ks (next QK) and V buffers
  }

  // ---- epilogue: reduce lr (keyed l15) across lg, transpose inv to oa rows, store ----
  #pragma unroll
  for (int m = 0; m < 2; ++m) {
    float l = lr[m];
    l += __shfl_xor(l, 16);
    l += __shfl_xor(l, 32);
    const float inv = 1.0f / l;                 // keyed l15
    const float i0 = __shfl(inv, lg * 4 + 0);   // row lg*4+r's inv from lane lg*4+r
    const float i1 = __shfl(inv, lg * 4 + 1);
    const float i2 = __shfl(inv, lg * 4 + 2);
    const float i3 = __shfl(inv, lg * 4 + 3);
    float* op = outg + ((size_t)(qgrp * 128 + wid * 32 + m * 16) * HH + h) * DD;
    #pragma unroll
    for (int nd = 0; nd < 8; ++nd) {
      const int d = nd * 16 + l15;
      op[(size_t)(lg * 4 + 0) * HH * DD + d] = oa[m][nd][0] * i0;
      op[(size_t)(lg * 4 + 1) * HH * DD + d] = oa[m][nd][1] * i1;
      op[(size_t)(lg * 4 + 2) * HH * DD + d] = oa[m][nd][2] * i2;
      op[(size_t)(lg * 4 + 3) * HH * DD + d] = oa[m][nd][3] * i3;
    }
  }
}

extern "C" void kernel_launch(void* const* d_in, const int* in_sizes, int n_in,
                              void* d_out, int out_size, void* d_ws, size_t ws_size,
                              hipStream_t stream) {
  const float* q = (const float*)d_in[0];
  const float* k = (const float*)d_in[1];
  const float* v = (const float*)d_in[2];
  float* out = (float*)d_out;
  const size_t elems = (size_t)HH * SS * DD;
  unsigned short* kbuf  = (unsigned short*)d_ws;
  unsigned short* vtbuf = kbuf + elems;

  conv_kv_kernel<<<dim3(NBQ, HH), 256, 0, stream>>>(k, v, kbuf, vtbuf);
  sparse_attn_v11<<<dim3(NBQ / 2 * HH), 256, 49152, stream>>>(q, kbuf, vtbuf, out);
}

// Round 13
// 113.497 us; speedup vs baseline: 1.0462x; 1.0462x over previous
//
#include <hip/hip_runtime.h>
#include <hip/hip_bf16.h>

#define HH 16
#define DD 128
#define NBQ 128
#define SS 8192

typedef __attribute__((ext_vector_type(4))) float f32x4;
typedef __attribute__((ext_vector_type(4))) short bf16x4;
typedef __attribute__((ext_vector_type(8))) short bf16x8;

// single-instruction HW convert (RNE)
__device__ __forceinline__ short f2bf_hw(float f) {
  __hip_bfloat16 b = __float2bfloat16(f);
  return __builtin_bit_cast(short, b);
}

__device__ __forceinline__ void gload_lds16(const void* g, void* l) {
  __builtin_amdgcn_global_load_lds(
      (const __attribute__((address_space(1))) void*)g,
      (__attribute__((address_space(3))) void*)l, 16, 0, 0);
}

// ---------------- prepass 1: K fp32 [s][h][d] -> bf16 [h][s][d] ----------------
__global__ __launch_bounds__(256)
void conv_k_kernel(const float* __restrict__ kg, unsigned short* __restrict__ kb) {
  const size_t e = ((size_t)blockIdx.x * 256 + threadIdx.x) * 4;  // out element idx
  const int h = (int)(e >> 20);           // S*D = 2^20
  const int s = (int)((e >> 7) & (SS - 1));
  const int d = (int)(e & 127);
  f32x4 a = *(const f32x4*)(kg + ((size_t)s * HH + h) * DD + d);
  bf16x4 o;
  o[0] = f2bf_hw(a[0]); o[1] = f2bf_hw(a[1]);
  o[2] = f2bf_hw(a[2]); o[3] = f2bf_hw(a[3]);
  *(bf16x4*)(kb + e) = o;
}

// ---- prepass 2: V fp32 [s][h][d] -> bf16 PV-frag-ordered blocks Vt2[h][kb][d][p] ----
// p = lg*16 + kt*4 + r  holds V[key = kt*16 + lg*4 + r][d]  (so one lane's 4 PV K-step
// fragments are 16 contiguous shorts -> 2x ds_read_b128 in the main kernel).
__global__ __launch_bounds__(256)
void conv_vt2_kernel(const float* __restrict__ vg, unsigned short* __restrict__ vt) {
  __shared__ unsigned short tile[128 * 72];  // [d][key] with +8 short pad per row
  const int kb = blockIdx.x, h = blockIdx.y, tid = threadIdx.x;
  {
    const int r = tid >> 2, q = tid & 3;   // r = key row, q = d-chunk
    const float* vp = vg + ((size_t)(kb * 64 + r) * HH + h) * DD + q * 32;
    #pragma unroll
    for (int c = 0; c < 8; ++c) {
      f32x4 a = *(const f32x4*)(vp + c * 4);
      #pragma unroll
      for (int j = 0; j < 4; ++j)
        tile[(q * 32 + c * 4 + j) * 72 + r] = (unsigned short)f2bf_hw(a[j]);
    }
  }
  __syncthreads();
  const int d = tid >> 1, half = tid & 1;
  unsigned short* op = vt + ((size_t)(h * NBQ + kb) * 128 + d) * 64 + half * 32;
  #pragma unroll
  for (int j = 0; j < 4; ++j) {
    bf16x8 f;
    #pragma unroll
    for (int e = 0; e < 8; ++e) {
      const int p = half * 32 + j * 8 + e;
      const int key = ((p >> 2) & 3) * 16 + (p >> 4) * 4 + (p & 3);
      f[e] = (short)tile[d * 72 + key];
    }
    *(bf16x8*)(op + j * 8) = f;
  }
}

// ------------- main kernel: v10-verified core + b128 PV reads (permuted Vt2) -------------
// 1 workgroup = (2 q-blocks, head), 4 waves x 32 rows. Swapped QK^T, in-register P,
// PV via 16x16x16 K-steps. 48KB LDS: K single-buffered, V double-buffered -> 3 wg/CU.
#define SWK(o) ((o) ^ ((((o) >> 8) & 7) << 4))
#define SWV(o) ((o) ^ ((((o) >> 7) & 7) << 4))

__global__ __launch_bounds__(256, 2)
void sparse_attn_v12(const float* __restrict__ qg_, const unsigned short* __restrict__ kbuf,
                     const unsigned short* __restrict__ vtbuf, float* __restrict__ outg) {
  extern __shared__ __align__(16) char lds[];
  // Ks: 0..16KB ([64 key][128 d] bf16 swz) | V buf b (b=0,1): 16384 + b*16384 (Vt2 swz)

  const int qgrp = blockIdx.x;   // 0..63
  const int h    = blockIdx.y;
  const int tid  = threadIdx.x;
  const int wid  = tid >> 6;
  const int lane = tid & 63;
  const int l15  = lane & 15;
  const int lg   = lane >> 4;

  const int qlo  = qgrp * 2, qhi = qgrp * 2 + 1;
  const int qb_w = qlo + (wid >> 1);          // this wave's q-block
  const int rib0 = (wid & 1) * 32;            // wave's row base within its q-block

  const int nv     = (qhi + 1 < 4) ? qhi + 1 : 4;
  const int wstart = (qlo - 3 > 4) ? qlo - 3 : 4;
  const int nw     = (qhi - wstart + 1 > 0) ? qhi - wstart + 1 : 0;
  const int nlist  = nv + nw;

  // 1/sqrt(128) * log2(e): exp2-domain softmax
  const float scale = 0.12752030522080552f;

  // ---- Q fragments (B operand: col j = q-row = l15, k = d = kc*32+lg*8+{0..7}) ----
  bf16x8 qa[2][4];
  #pragma unroll
  for (int m = 0; m < 2; ++m) {
    const float* qp = qg_ + ((size_t)(qgrp * 128 + wid * 32 + m * 16 + l15) * HH + h) * DD;
    #pragma unroll
    for (int kc = 0; kc < 4; ++kc) {
      const int d0 = kc * 32 + lg * 8;
      f32x4 a = *(const f32x4*)(qp + d0);
      f32x4 b = *(const f32x4*)(qp + d0 + 4);
      bf16x8 f;
      f[0] = f2bf_hw(a[0] * scale); f[1] = f2bf_hw(a[1] * scale);
      f[2] = f2bf_hw(a[2] * scale); f[3] = f2bf_hw(a[3] * scale);
      f[4] = f2bf_hw(b[0] * scale); f[5] = f2bf_hw(b[1] * scale);
      f[6] = f2bf_hw(b[2] * scale); f[7] = f2bf_hw(b[3] * scale);
      qa[m][kc] = f;
    }
  }

  // oa[m][nd][r] = O[q-row = lg*4+r (of m-tile)][d = nd*16+l15]
  f32x4 oa[2][8];
  #pragma unroll
  for (int m = 0; m < 2; ++m)
    #pragma unroll
    for (int i = 0; i < 8; ++i) oa[m][i] = (f32x4){0.f, 0.f, 0.f, 0.f};
  float mr[2] = {-1e30f, -1e30f};   // running row max, keyed q-row = l15 (row-uniform)
  float lr[2] = {0.f, 0.f};         // lane-partial row sum, keyed l15

  const char* kbase = (const char*)kbuf + ((size_t)h * NBQ << 14);
  const char* vbase = (const char*)vtbuf + ((size_t)h * NBQ << 14);

  // prologue: stage list[0] (= block 0): K -> Ks, V -> vbuf0
  {
    #pragma unroll
    for (int p = 0; p < 4; ++p) {
      const int ob = p * 4096 + wid * 1024;
      const int o  = ob + lane * 16;
      gload_lds16(kbase + SWK(o), lds + ob);
      gload_lds16(vbase + SWV(o), lds + 16384 + ob);
    }
  }
  __syncthreads();

  for (int t = 0; t < nlist; ++t) {
    const int kb = (t < nv) ? t : (wstart + (t - nv));
    const bool valid = (kb <= qb_w) && ((qb_w - kb < 4) || (kb < 4));
    char* Vb = lds + 16384 + (t & 1) * 16384;

    // ---- S^T = K Q^T : s[m][kt][r] = S[q=l15 (m-tile)][key = kt*16+lg*4+r] ----
    f32x4 s[2][4];
    if (valid) {
      #pragma unroll
      for (int m = 0; m < 2; ++m)
        #pragma unroll
        for (int kt = 0; kt < 4; ++kt) s[m][kt] = (f32x4){0.f, 0.f, 0.f, 0.f};
      __builtin_amdgcn_s_setprio(1);
      #pragma unroll
      for (int kt = 0; kt < 4; ++kt) {
        const int key = kt * 16 + l15;   // A-frag row = l15
        #pragma unroll
        for (int kc = 0; kc < 4; ++kc) {
          const int off = (key * 256 + (kc * 32 + lg * 8) * 2) ^ ((key & 7) << 4);
          bf16x8 kf = *(const bf16x8*)(lds + off);   // A: K[key][d]  (Ks at base 0)
          s[0][kt] = __builtin_amdgcn_mfma_f32_16x16x32_bf16(kf, qa[0][kc], s[0][kt], 0, 0, 0);
          s[1][kt] = __builtin_amdgcn_mfma_f32_16x16x32_bf16(kf, qa[1][kc], s[1][kt], 0, 0, 0);
        }
      }
      __builtin_amdgcn_s_setprio(0);
    }

    __syncthreads();   // barrier1: all waves done reading Ks (no vmem outstanding -> cheap)

    // ---- issue async stages for t+1: K(t+1) -> Ks (safe now), V(t+1) -> other V buf ----
    if (t + 1 < nlist) {
      const int kbn = (t + 1 < nv) ? (t + 1) : (wstart + (t + 1 - nv));
      const char* ksrc = kbase + ((size_t)kbn << 14);
      const char* vsrc = vbase + ((size_t)kbn << 14);
      char* Vd = lds + 16384 + ((t + 1) & 1) * 16384;
      #pragma unroll
      for (int p = 0; p < 4; ++p) {
        const int ob = p * 4096 + wid * 1024;
        const int o  = ob + lane * 16;
        gload_lds16(ksrc + SWK(o), lds + ob);
        gload_lds16(vsrc + SWV(o), Vd + ob);
      }
    }

    if (valid) {
      // ---- diagonal block: element-level causal mask (q = l15, key = kt*16+lg*4+r) ----
      if (kb == qb_w) {
        #pragma unroll
        for (int m = 0; m < 2; ++m) {
          const int rib = rib0 + m * 16 + l15;   // q-row within block
          #pragma unroll
          for (int kt = 0; kt < 4; ++kt)
            #pragma unroll
            for (int r = 0; r < 4; ++r) {
              const int key = kt * 16 + lg * 4 + r;
              if (rib < key) s[m][kt][r] = -1e30f;
            }
        }
      }

      // ---- softmax (exp2 domain, defer-max THR=8, lane-partial sum) ----
      #pragma unroll
      for (int m = 0; m < 2; ++m) {
        float a0 = fmaxf(fmaxf(s[m][0][0], s[m][0][1]), fmaxf(s[m][0][2], s[m][0][3]));
        float a1 = fmaxf(fmaxf(s[m][1][0], s[m][1][1]), fmaxf(s[m][1][2], s[m][1][3]));
        float a2 = fmaxf(fmaxf(s[m][2][0], s[m][2][1]), fmaxf(s[m][2][2], s[m][2][3]));
        float a3 = fmaxf(fmaxf(s[m][3][0], s[m][3][1]), fmaxf(s[m][3][2], s[m][3][3]));
        float lanemax = fmaxf(fmaxf(a0, a1), fmaxf(a2, a3));
        if (!__all(lanemax <= mr[m] + 8.f)) {
          float mx = lanemax;
          mx = fmaxf(mx, __shfl_xor(mx, 16));
          mx = fmaxf(mx, __shfl_xor(mx, 32));     // row max (uniform across lg)
          const float mnew = fmaxf(mr[m], mx);
          const float sc = __builtin_amdgcn_exp2f(mr[m] - mnew);
          lr[m] *= sc;                             // lr keyed l15: direct
          mr[m] = mnew;
          // transpose sc to oa rows: row (lg*4+r)'s sc lives in lane (lg*4+r)
          const float s0 = __shfl(sc, lg * 4 + 0);
          const float s1 = __shfl(sc, lg * 4 + 1);
          const float s2 = __shfl(sc, lg * 4 + 2);
          const float s3 = __shfl(sc, lg * 4 + 3);
          #pragma unroll
          for (int nd = 0; nd < 8; ++nd) {
            oa[m][nd][0] *= s0; oa[m][nd][1] *= s1;
            oa[m][nd][2] *= s2; oa[m][nd][3] *= s3;
          }
        }
        float lsum = 0.f;
        #pragma unroll
        for (int kt = 0; kt < 4; ++kt)
          #pragma unroll
          for (int r = 0; r < 4; ++r) {
            const float p = __builtin_amdgcn_exp2f(s[m][kt][r] - mr[m]);
            s[m][kt][r] = p;
            lsum += p;
          }
        lr[m] += lsum;
      }

      // ---- pack P in-register: pa[m][kt] = A-frag (row=l15, k=lg*4+{0..3}) ----
      bf16x4 pa[2][4];
      #pragma unroll
      for (int m = 0; m < 2; ++m)
        #pragma unroll
        for (int kt = 0; kt < 4; ++kt) {
          unsigned u0 = (unsigned)(unsigned short)f2bf_hw(s[m][kt][0]) |
                        ((unsigned)(unsigned short)f2bf_hw(s[m][kt][1]) << 16);
          unsigned u1 = (unsigned)(unsigned short)f2bf_hw(s[m][kt][2]) |
                        ((unsigned)(unsigned short)f2bf_hw(s[m][kt][3]) << 16);
          uint2 uu; uu.x = u0; uu.y = u1;
          pa[m][kt] = __builtin_bit_cast(bf16x4, uu);
        }

      // ---- O += P V : b128 reads (Vt2 layout), 2 K-step frags per read ----
      __builtin_amdgcn_s_setprio(1);
      #pragma unroll
      for (int nd = 0; nd < 8; ++nd) {
        const int d = nd * 16 + l15;
        #pragma unroll
        for (int hb = 0; hb < 2; ++hb) {
          const int off = (d * 128 + lg * 32 + hb * 16) ^ ((d & 7) << 4);
          bf16x8 v2 = *(const bf16x8*)(Vb + off);
          bf16x4 vlo = __builtin_shufflevector(v2, v2, 0, 1, 2, 3);
          bf16x4 vhi = __builtin_shufflevector(v2, v2, 4, 5, 6, 7);
          oa[0][nd] = __builtin_amdgcn_mfma_f32_16x16x16bf16_1k(pa[0][2 * hb],     vlo, oa[0][nd], 0, 0, 0);
          oa[1][nd] = __builtin_amdgcn_mfma_f32_16x16x16bf16_1k(pa[1][2 * hb],     vlo, oa[1][nd], 0, 0, 0);
          oa[0][nd] = __builtin_amdgcn_mfma_f32_16x16x16bf16_1k(pa[0][2 * hb + 1], vhi, oa[0][nd], 0, 0, 0);
          oa[1][nd] = __builtin_amdgcn_mfma_f32_16x16x16bf16_1k(pa[1][2 * hb + 1], vhi, oa[1][nd], 0, 0, 0);
        }
      }
      __builtin_amdgcn_s_setprio(0);
    }
    __syncthreads();  // barrier2: drains K/V DMA; protects Ks (next QK) and V buffers
  }

  // ---- epilogue: reduce lr (keyed l15) across lg, transpose inv to oa rows, store ----
  #pragma unroll
  for (int m = 0; m < 2; ++m) {
    float l = lr[m];
    l += __shfl_xor(l, 16);
    l += __shfl_xor(l, 32);
    const float inv = 1.0f / l;                 // keyed l15
    const float i0 = __shfl(inv, lg * 4 + 0);   // row lg*4+r's inv from lane lg*4+r
    const float i1 = __shfl(inv, lg * 4 + 1);
    const float i2 = __shfl(inv, lg * 4 + 2);
    const float i3 = __shfl(inv, lg * 4 + 3);
    float* op = outg + ((size_t)(qgrp * 128 + wid * 32 + m * 16) * HH + h) * DD;
    #pragma unroll
    for (int nd = 0; nd < 8; ++nd) {
      const int d = nd * 16 + l15;
      op[(size_t)(lg * 4 + 0) * HH * DD + d] = oa[m][nd][0] * i0;
      op[(size_t)(lg * 4 + 1) * HH * DD + d] = oa[m][nd][1] * i1;
      op[(size_t)(lg * 4 + 2) * HH * DD + d] = oa[m][nd][2] * i2;
      op[(size_t)(lg * 4 + 3) * HH * DD + d] = oa[m][nd][3] * i3;
    }
  }
}

extern "C" void kernel_launch(void* const* d_in, const int* in_sizes, int n_in,
                              void* d_out, int out_size, void* d_ws, size_t ws_size,
                              hipStream_t stream) {
  const float* q = (const float*)d_in[0];
  const float* k = (const float*)d_in[1];
  const float* v = (const float*)d_in[2];
  float* out = (float*)d_out;
  const size_t elems = (size_t)HH * SS * DD;
  unsigned short* kbuf  = (unsigned short*)d_ws;
  unsigned short* vtbuf = kbuf + elems;

  conv_k_kernel<<<(int)(elems / 4 / 256), 256, 0, stream>>>(k, kbuf);
  conv_vt2_kernel<<<dim3(NBQ, HH), 256, 0, stream>>>(v, vtbuf);
  sparse_attn_v12<<<dim3(NBQ / 2, HH), 256, 49152, stream>>>(q, kbuf, vtbuf, out);
}